// Round 6
// baseline (657.382 us; speedup 1.0000x reference)
//
#include <hip/hip_runtime.h>
#include <math.h>

namespace {
constexpr int kB = 2, kN = 2048, kDim = 256, kH = 8, kDH = 32;
constexpr int kBH = kB * kH;
constexpr long kPlane = (long)kBH * kN * kDH;  // 1,048,576 elems per tensor
// DH^-0.5 / ln2 folded into stored q so softmax weight = exp2(score)
constexpr float kQScaleL2 = 0.25506852552f;
}

typedef unsigned short u16;
typedef short short8 __attribute__((ext_vector_type(8)));
typedef short short4v __attribute__((ext_vector_type(4)));
typedef float floatx16 __attribute__((ext_vector_type(16)));
#define MFMA_BF16(a, b, c) __builtin_amdgcn_mfma_f32_32x32x16_bf16(a, b, c, 0, 0, 0)

__device__ inline u16 bf16b(float x) {
    union { float f; unsigned u; } c; c.f = x;
    unsigned r = c.u + 0x7FFFu + ((c.u >> 16) & 1u);
    return (u16)(r >> 16);
}
__device__ inline unsigned pack2(float x, float y) {
    return (unsigned)bf16b(x) | ((unsigned)bf16b(y) << 16);
}
// truncating bf16 pack of two positive floats via one v_perm_b32
__device__ inline unsigned packtr(float lo, float hi) {
    return __builtin_amdgcn_perm(__float_as_uint(hi), __float_as_uint(lo), 0x07060302u);
}
__device__ inline short8 mk8(const float* e) {
    union { unsigned u[4]; short8 s; } c;
    c.u[0] = packtr(e[0], e[1]);
    c.u[1] = packtr(e[2], e[3]);
    c.u[2] = packtr(e[4], e[5]);
    c.u[3] = packtr(e[6], e[7]);
    return c.s;
}

// ---------------------------------------------------------------------------
// Build doubled/transposed bf16 weight matrices (unchanged).
// ---------------------------------------------------------------------------
__global__ __launch_bounds__(256, 2) void prep_w(
    const float* __restrict__ wq_r, const float* __restrict__ wq_i,
    const float* __restrict__ wkv_r, const float* __restrict__ wkv_i,
    const float* __restrict__ wo_r, const float* __restrict__ wo_i,
    u16* __restrict__ Wbig, u16* __restrict__ WoT)
{
    const long base = ((long)blockIdx.x * 256 + threadIdx.x) * 4;
    if (base < 786432) {
        const int c = (int)(base >> 9);
        const int k = (int)(base & 511);
        const int g = c >> 8, d = c & 255;
        const bool hi = k >= 256;
        const int k2 = hi ? k - 256 : k;
        const float* src;
        float sgn = 1.f;
        int col, stride;
        if (g < 2) {
            stride = 256; col = d;
            if (g == 0) { src = hi ? wq_i : wq_r; if (hi) sgn = -1.f; }
            else        { src = hi ? wq_r : wq_i; }
            sgn *= kQScaleL2;
        } else {
            stride = 512;
            col = (g >= 4) ? d + 256 : d;
            if ((g & 1) == 0) { src = hi ? wkv_i : wkv_r; if (hi) sgn = -1.f; }
            else              { src = hi ? wkv_r : wkv_i; }
        }
        short4v v;
        #pragma unroll
        for (int j = 0; j < 4; ++j)
            v[j] = (short)bf16b(src[(long)(k2 + j) * stride + col] * sgn);
        *(short4v*)(Wbig + base) = v;
    } else {
        const long o = base - 786432;
        const int c = (int)(o >> 9);
        const int k = (int)(o & 511);
        const bool hi = k >= 256;
        const int k2 = hi ? k - 256 : k;
        const float* src;
        float sgn = 1.f;
        int col;
        if (c < 256) { col = c;       src = hi ? wo_i : wo_r; if (hi) sgn = -1.f; }
        else         { col = c - 256; src = hi ? wo_r : wo_i; }
        short4v v;
        #pragma unroll
        for (int j = 0; j < 4; ++j)
            v[j] = (short)bf16b(src[(long)(k2 + j) * 256 + col] * sgn);
        *(short4v*)(WoT + o) = v;
    }
}

// ---------------------------------------------------------------------------
// QKV projection GEMM (unchanged). v stored transposed per head:
// vrT/viT [bh][32 d][2048 n].
// ---------------------------------------------------------------------------
__global__ __launch_bounds__(256, 2) void gemm_proj(
    const float* __restrict__ xr_g, const float* __restrict__ xi_g,
    const u16* __restrict__ BT,
    u16* __restrict__ qr, u16* __restrict__ qi, u16* __restrict__ kr,
    u16* __restrict__ ki, u16* __restrict__ vrT, u16* __restrict__ viT)
{
    __shared__ __align__(16) u16 sA[128 * 32];
    __shared__ __align__(16) u16 sB[128 * 32];
    const int tid = threadIdx.x;
    const int lane = tid & 63, l31 = lane & 31, lh = lane >> 5;
    const int w = tid >> 6, wrow = w & 1, wcol = w >> 1;
    const int srow = tid >> 2, sseg = tid & 3;
    const int n0 = blockIdx.x * 128, m0 = blockIdx.y * 128;

    floatx16 a00 = {0}, a01 = {0}, a10 = {0}, a11 = {0};

    for (int kt = 0; kt < 512; kt += 32) {
        __syncthreads();
        const float* xbase = (kt < 256) ? xr_g : xi_g;
        const int kc = (kt & 255) + sseg * 8;
        #pragma unroll
        for (int i = 0; i < 2; ++i) {
            const int r = srow + i * 64;
            {
                const float* src = xbase + (long)(m0 + r) * 256 + kc;
                const float4 f0 = *(const float4*)(src);
                const float4 f1 = *(const float4*)(src + 4);
                short8 v;
                v[0] = (short)bf16b(f0.x); v[1] = (short)bf16b(f0.y);
                v[2] = (short)bf16b(f0.z); v[3] = (short)bf16b(f0.w);
                v[4] = (short)bf16b(f1.x); v[5] = (short)bf16b(f1.y);
                v[6] = (short)bf16b(f1.z); v[7] = (short)bf16b(f1.w);
                *(short8*)(sA + r * 32 + sseg * 8) = v;
            }
            *(short8*)(sB + r * 32 + sseg * 8) =
                *(const short8*)(BT + (long)(n0 + r) * 512 + kt + sseg * 8);
        }
        __syncthreads();
        #pragma unroll
        for (int s = 0; s < 2; ++s) {
            const int ko = s * 16 + lh * 8;
            const short8 fa0 = *(const short8*)(sA + (wrow * 64 + l31) * 32 + ko);
            const short8 fa1 = *(const short8*)(sA + (wrow * 64 + 32 + l31) * 32 + ko);
            const short8 fb0 = *(const short8*)(sB + (wcol * 64 + l31) * 32 + ko);
            const short8 fb1 = *(const short8*)(sB + (wcol * 64 + 32 + l31) * 32 + ko);
            a00 = MFMA_BF16(fa0, fb0, a00);
            a01 = MFMA_BF16(fa0, fb1, a01);
            a10 = MFMA_BF16(fa1, fb0, a10);
            a11 = MFMA_BF16(fa1, fb1, a11);
        }
    }

    floatx16 accs[2][2] = {{a00, a01}, {a10, a11}};
    #pragma unroll
    for (int rt = 0; rt < 2; ++rt) {
        #pragma unroll
        for (int ct = 0; ct < 2; ++ct) {
            const int colb = n0 + wcol * 64 + ct * 32;
            const int g = colb >> 8;
            const int h = (colb & 255) >> 5;
            if (g < 4) {
                u16* pl = (g == 0) ? qr : (g == 1) ? qi : (g == 2) ? kr : ki;
                #pragma unroll
                for (int reg = 0; reg < 16; ++reg) {
                    const int row = m0 + wrow * 64 + rt * 32 + (reg & 3) + 8 * (reg >> 2) + 4 * lh;
                    const int b = row >> 11, nn = row & 2047;
                    pl[(((long)(b * 8 + h)) * 2048 + nn) * 32 + l31] = bf16b(accs[rt][ct][reg]);
                }
            } else {
                u16* pl = (g == 4) ? vrT : viT;
                #pragma unroll
                for (int reg = 0; reg < 16; ++reg) {
                    const int row = m0 + wrow * 64 + rt * 32 + (reg & 3) + 8 * (reg >> 2) + 4 * lh;
                    const int b = row >> 11, nn = row & 2047;
                    pl[(((long)(b * 8 + h)) * 32 + l31) * 2048 + nn] = bf16b(accs[rt][ct][reg]);
                }
            }
        }
    }
}

// ---------------------------------------------------------------------------
// MFMA flash attention v3.
//  - Block = 32 queries; 4 waves = (qtype 0/1) x (jhalf 0/1); grid 64x16.
//  - S^T = K.Q^T with K A-frags loaded DIRECTLY from global (L2-resident).
//  - V staged in LDS with key-permuted layout pi so the PV B-operand is
//    built from each lane's own exp regs: 4 v_perm packs, no shuffles.
//    pi = [0-3,8-11,4-7,12-15 | 16-19,24-27,20-23,28-31]
//  - j-split partials merged via LDS po-exchange (normalization is linear).
// ---------------------------------------------------------------------------
__global__ __launch_bounds__(256, 4) void attn_kernel(
    const u16* __restrict__ qr_g, const u16* __restrict__ qi_g,
    const u16* __restrict__ kr_g, const u16* __restrict__ ki_g,
    const u16* __restrict__ vrT_g, const u16* __restrict__ viT_g,
    u16* __restrict__ xo)
{
    // staging: [jhalf][buf] 64x40 u16 = 20480 B, overlaid by merge:
    // sLa [4][2][64] f32 (2048 B) + sPo [4][64][33] f32 (33792 B) = 35840 B
    __shared__ __align__(16) unsigned char smem[35840];

    const int tid = threadIdx.x;
    const int lane = tid & 63, l31 = lane & 31, lh = lane >> 5;
    const int w = tid >> 6, qtype = w & 1, jhalf = w >> 1;
    const int bh = blockIdx.y;
    const int i0 = blockIdx.x * 32;
    const long base = (long)bh * kN * kDH;

    u16* sV0 = (u16*)smem + (size_t)jhalf * (2 * 64 * 40);

    // Q B-frags (lane = query column l31, k = d)
    const u16* qg = (qtype ? qi_g : qr_g) + base;
    short8 qB0, qB1;
    {
        const u16* qp = qg + (long)(i0 + l31) * kDH;
        qB0 = *(const short8*)(qp + lh * 8);
        qB1 = *(const short8*)(qp + 16 + lh * 8);
    }

    // V staging roles: 128 threads per jhalf, each covers 2 key-segments
    const int tid128 = tid & 127;
    const int srow = tid128 & 63;                    // vcol (vr 0-31 | vi 32-63)
    const int sg = tid128 >> 6;                      // segs {sg, sg+2}
    const u16* vplane = ((srow < 32) ? vrT_g : viT_g)
                      + ((long)bh * 32 + (srow & 31)) * kN;
    const int s0 = sg, s1 = sg + 2;
    const int p0 = ((s0 >> 1) * 16) + ((s0 & 1) * 4);  // permuted positions
    const int p1 = ((s1 >> 1) * 16) + ((s1 & 1) * 4);

    const int tbase = jhalf * 32;
    short8 vpre0 = *(const short8*)(vplane + (long)tbase * 32 + s0 * 8);
    short8 vpre1 = *(const short8*)(vplane + (long)tbase * 32 + s1 * 8);

    const u16* kA = kr_g + base;
    const u16* kBp = ki_g + base;

    floatx16 U0r = {0}, U0i = {0}, U1r = {0}, U1i = {0};
    float La0 = 0.f, La1 = 0.f;

    for (int tt = 0; tt < 32; ++tt) {
        const int t = tbase + tt;
        u16* bV = sV0 + (tt & 1) * (64 * 40);
        {   // permuted V store: 4 ds_write_b64
            union { short8 s; short4v h[2]; } c0, c1;
            c0.s = vpre0; c1.s = vpre1;
            *(short4v*)(bV + srow * 40 + p0)     = c0.h[0];
            *(short4v*)(bV + srow * 40 + p0 + 8) = c0.h[1];
            *(short4v*)(bV + srow * 40 + p1)     = c1.h[0];
            *(short4v*)(bV + srow * 40 + p1 + 8) = c1.h[1];
        }
        __syncthreads();
        if (tt < 31) {
            vpre0 = *(const short8*)(vplane + (long)(t + 1) * 32 + s0 * 8);
            vpre1 = *(const short8*)(vplane + (long)(t + 1) * 32 + s1 * 8);
        }

        // K A-frags direct from global (lane = key row l31, k = d)
        const long krow = (long)(t * 32 + l31) * kDH + lh * 8;
        const short8 ka0 = *(const short8*)(kA + krow);
        const short8 ka1 = *(const short8*)(kA + krow + 16);
        const short8 kb0 = *(const short8*)(kBp + krow);
        const short8 kb1 = *(const short8*)(kBp + krow + 16);

        floatx16 S0 = {0}, S1 = {0};
        S0 = MFMA_BF16(ka0, qB0, S0);
        S0 = MFMA_BF16(ka1, qB1, S0);
        S1 = MFMA_BF16(kb0, qB0, S1);
        S1 = MFMA_BF16(kb1, qB1, S1);

        float e0[16], e1[16];
        #pragma unroll
        for (int r = 0; r < 16; ++r) {
            e0[r] = __builtin_amdgcn_exp2f(S0[r]);
            La0 += e0[r];
        }
        #pragma unroll
        for (int r = 0; r < 16; ++r) {
            e1[r] = __builtin_amdgcn_exp2f(S1[r]);
            La1 += e1[r];
        }
        const short8 F0a = mk8(&e0[0]);
        const short8 F0b = mk8(&e0[8]);
        const short8 F1a = mk8(&e1[0]);
        const short8 F1b = mk8(&e1[8]);

        // V^T A-frags from permuted LDS rows
        const u16* vra = bV + l31 * 40;
        const u16* vrb = bV + (32 + l31) * 40;
        const short8 va0 = *(const short8*)(vra + lh * 8);
        const short8 va1 = *(const short8*)(vra + 16 + lh * 8);
        const short8 vb0 = *(const short8*)(vrb + lh * 8);
        const short8 vb1 = *(const short8*)(vrb + 16 + lh * 8);

        U0r = MFMA_BF16(va0, F0a, U0r);
        U0r = MFMA_BF16(va1, F0b, U0r);
        U0i = MFMA_BF16(vb0, F0a, U0i);
        U0i = MFMA_BF16(vb1, F0b, U0i);
        U1r = MFMA_BF16(va0, F1a, U1r);
        U1r = MFMA_BF16(va1, F1b, U1r);
        U1i = MFMA_BF16(vb0, F1a, U1i);
        U1i = MFMA_BF16(vb1, F1b, U1i);
    }

    La0 += __shfl_xor(La0, 32);
    La1 += __shfl_xor(La1, 32);

    __syncthreads();   // staging dead; overlay merge scratch
    float* sLa = (float*)smem;                 // [4][2][64]
    float* sPo = (float*)(smem + 2048);        // [4][64][33]
    sLa[(w * 2 + 0) * 64 + lane] = La0;
    sLa[(w * 2 + 1) * 64 + lane] = La1;
    __syncthreads();
    const int pw = w ^ 2;                      // jhalf partner, same qtype
    const float iL0 = 1.f / (La0 + sLa[(pw * 2 + 0) * 64 + lane]);
    const float iL1 = 1.f / (La1 + sLa[(pw * 2 + 1) * 64 + lane]);

    float po_r[16], po_i[16];
    #pragma unroll
    for (int r = 0; r < 16; ++r) {
        if (qtype == 0) {
            po_r[r] =  U0r[r] * iL0 - U1i[r] * iL1;
            po_i[r] =  U0i[r] * iL0 + U1r[r] * iL1;
        } else {
            po_r[r] = -U0i[r] * iL0 - U1r[r] * iL1;
            po_i[r] =  U0r[r] * iL0 - U1i[r] * iL1;
        }
    }

    if (w != 0) {
        float* dst = sPo + ((size_t)w * 64 + lane) * 33;
        #pragma unroll
        for (int g = 0; g < 4; ++g) {
            *(float4*)(dst + 4 * g) =
                make_float4(po_r[4 * g], po_r[4 * g + 1], po_r[4 * g + 2], po_r[4 * g + 3]);
            *(float4*)(dst + 16 + 4 * g) =
                make_float4(po_i[4 * g], po_i[4 * g + 1], po_i[4 * g + 2], po_i[4 * g + 3]);
        }
    }
    __syncthreads();
    if (w == 0) {
        #pragma unroll
        for (int pw2 = 1; pw2 < 4; ++pw2) {
            const float* src = sPo + ((size_t)pw2 * 64 + lane) * 33;
            #pragma unroll
            for (int g = 0; g < 4; ++g) {
                const float4 ar = *(const float4*)(src + 4 * g);
                const float4 ai = *(const float4*)(src + 16 + 4 * g);
                po_r[4 * g + 0] += ar.x; po_r[4 * g + 1] += ar.y;
                po_r[4 * g + 2] += ar.z; po_r[4 * g + 3] += ar.w;
                po_i[4 * g + 0] += ai.x; po_i[4 * g + 1] += ai.y;
                po_i[4 * g + 2] += ai.z; po_i[4 * g + 3] += ai.w;
            }
        }
        const int b = bh >> 3, h = bh & 7;
        u16* xrow = xo + ((long)(b * 2048) + i0 + l31) * 512 + h * 32;
        #pragma unroll
        for (int g = 0; g < 4; ++g) {
            const int d0 = 8 * g + 4 * lh;
            union { unsigned u[2]; uint2 v; } pr, pi;
            pr.u[0] = pack2(po_r[4 * g + 0], po_r[4 * g + 1]);
            pr.u[1] = pack2(po_r[4 * g + 2], po_r[4 * g + 3]);
            pi.u[0] = pack2(po_i[4 * g + 0], po_i[4 * g + 1]);
            pi.u[1] = pack2(po_i[4 * g + 2], po_i[4 * g + 3]);
            *(uint2*)(xrow + d0) = pr.v;
            *(uint2*)(xrow + 256 + d0) = pi.v;
        }
    }
}

// ---------------------------------------------------------------------------
// Output projection GEMM (unchanged).
// ---------------------------------------------------------------------------
__global__ __launch_bounds__(256, 2) void gemm_oproj(
    const u16* __restrict__ Xo, const u16* __restrict__ BT, float* __restrict__ out)
{
    __shared__ __align__(16) u16 sA[128 * 32];
    __shared__ __align__(16) u16 sB[128 * 32];
    const int tid = threadIdx.x;
    const int lane = tid & 63, l31 = lane & 31, lh = lane >> 5;
    const int w = tid >> 6, wrow = w & 1, wcol = w >> 1;
    const int srow = tid >> 2, sseg = tid & 3;
    const int n0 = blockIdx.x * 128, m0 = blockIdx.y * 128;

    floatx16 a00 = {0}, a01 = {0}, a10 = {0}, a11 = {0};

    for (int kt = 0; kt < 512; kt += 32) {
        __syncthreads();
        #pragma unroll
        for (int i = 0; i < 2; ++i) {
            const int r = srow + i * 64;
            *(short8*)(sA + r * 32 + sseg * 8) =
                *(const short8*)(Xo + (long)(m0 + r) * 512 + kt + sseg * 8);
            *(short8*)(sB + r * 32 + sseg * 8) =
                *(const short8*)(BT + (long)(n0 + r) * 512 + kt + sseg * 8);
        }
        __syncthreads();
        #pragma unroll
        for (int s = 0; s < 2; ++s) {
            const int ko = s * 16 + lh * 8;
            const short8 fa0 = *(const short8*)(sA + (wrow * 64 + l31) * 32 + ko);
            const short8 fa1 = *(const short8*)(sA + (wrow * 64 + 32 + l31) * 32 + ko);
            const short8 fb0 = *(const short8*)(sB + (wcol * 64 + l31) * 32 + ko);
            const short8 fb1 = *(const short8*)(sB + (wcol * 64 + 32 + l31) * 32 + ko);
            a00 = MFMA_BF16(fa0, fb0, a00);
            a01 = MFMA_BF16(fa0, fb1, a01);
            a10 = MFMA_BF16(fa1, fb0, a10);
            a11 = MFMA_BF16(fa1, fb1, a11);
        }
    }

    floatx16 accs[2][2] = {{a00, a01}, {a10, a11}};
    #pragma unroll
    for (int rt = 0; rt < 2; ++rt) {
        #pragma unroll
        for (int ct = 0; ct < 2; ++ct) {
            const int colb = n0 + wcol * 64 + ct * 32;
            #pragma unroll
            for (int reg = 0; reg < 16; ++reg) {
                const int row = m0 + wrow * 64 + rt * 32 + (reg & 3) + 8 * (reg >> 2) + 4 * lh;
                const int col = colb + l31;
                const float val = accs[rt][ct][reg];
                if (colb < 256) out[(long)row * 512 + col * 2] = val;
                else            out[(long)row * 512 + (col - 256) * 2 + 1] = val;
            }
        }
    }
}

extern "C" void kernel_launch(void* const* d_in, const int* in_sizes, int n_in,
                              void* d_out, int out_size, void* d_ws, size_t ws_size,
                              hipStream_t stream) {
    const float* xr    = (const float*)d_in[0];
    const float* xi    = (const float*)d_in[1];
    const float* wq_r  = (const float*)d_in[2];
    const float* wq_i  = (const float*)d_in[3];
    const float* wkv_r = (const float*)d_in[4];
    const float* wkv_i = (const float*)d_in[5];
    const float* wo_r  = (const float*)d_in[6];
    const float* wo_i  = (const float*)d_in[7];
    float* out = (float*)d_out;

    u16* ws16 = (u16*)d_ws;
    u16* qr   = ws16 + 0 * kPlane;
    u16* qi   = ws16 + 1 * kPlane;
    u16* kr   = ws16 + 2 * kPlane;
    u16* ki   = ws16 + 3 * kPlane;
    u16* vrT  = ws16 + 4 * kPlane;
    u16* viT  = ws16 + 5 * kPlane;
    u16* xo   = ws16 + 6 * kPlane;               // 2,097,152 elems
    u16* Wbig = ws16 + 8 * kPlane;               // 786,432 elems
    u16* WoT  = Wbig + 786432;                   // 262,144 elems

    prep_w<<<1024, 256, 0, stream>>>(wq_r, wq_i, wkv_r, wkv_i, wo_r, wo_i, Wbig, WoT);
    gemm_proj<<<dim3(12, 32), 256, 0, stream>>>(xr, xi, Wbig, qr, qi, kr, ki, vrT, viT);
    attn_kernel<<<dim3(kN / 32, kBH), 256, 0, stream>>>(qr, qi, kr, ki, vrT, viT, xo);
    gemm_oproj<<<dim3(4, 32), 256, 0, stream>>>(xo, WoT, out);
}

// Round 7
// 171.324 us; speedup vs baseline: 3.8371x; 3.8371x over previous
//
#include <hip/hip_runtime.h>
#include <math.h>

namespace {
constexpr int kB = 2, kN = 2048, kDim = 256, kH = 8, kDH = 32;
constexpr int kBH = kB * kH;
constexpr long kPlane = (long)kBH * kN * kDH;  // 1,048,576 elems per tensor
// DH^-0.5 / ln2 folded into stored q so softmax weight = exp2(score)
constexpr float kQScaleL2 = 0.25506852552f;
}

typedef unsigned short u16;
typedef short short8 __attribute__((ext_vector_type(8)));
typedef short short4v __attribute__((ext_vector_type(4)));
typedef float floatx16 __attribute__((ext_vector_type(16)));
#define MFMA_BF16(a, b, c) __builtin_amdgcn_mfma_f32_32x32x16_bf16(a, b, c, 0, 0, 0)

__device__ inline u16 bf16b(float x) {
    union { float f; unsigned u; } c; c.f = x;
    unsigned r = c.u + 0x7FFFu + ((c.u >> 16) & 1u);
    return (u16)(r >> 16);
}
__device__ inline unsigned pack2(float x, float y) {
    return (unsigned)bf16b(x) | ((unsigned)bf16b(y) << 16);
}
// truncating bf16 pack of two positive floats via one v_perm_b32
__device__ inline unsigned packtr(float lo, float hi) {
    return __builtin_amdgcn_perm(__float_as_uint(hi), __float_as_uint(lo), 0x07060302u);
}
__device__ inline short8 mk8(const float* e) {
    union { unsigned u[4]; short8 s; } c;
    c.u[0] = packtr(e[0], e[1]);
    c.u[1] = packtr(e[2], e[3]);
    c.u[2] = packtr(e[4], e[5]);
    c.u[3] = packtr(e[6], e[7]);
    return c.s;
}

// ---------------------------------------------------------------------------
// Build doubled/transposed bf16 weight matrices (unchanged).
// ---------------------------------------------------------------------------
__global__ __launch_bounds__(256, 2) void prep_w(
    const float* __restrict__ wq_r, const float* __restrict__ wq_i,
    const float* __restrict__ wkv_r, const float* __restrict__ wkv_i,
    const float* __restrict__ wo_r, const float* __restrict__ wo_i,
    u16* __restrict__ Wbig, u16* __restrict__ WoT)
{
    const long base = ((long)blockIdx.x * 256 + threadIdx.x) * 4;
    if (base < 786432) {
        const int c = (int)(base >> 9);
        const int k = (int)(base & 511);
        const int g = c >> 8, d = c & 255;
        const bool hi = k >= 256;
        const int k2 = hi ? k - 256 : k;
        const float* src;
        float sgn = 1.f;
        int col, stride;
        if (g < 2) {
            stride = 256; col = d;
            if (g == 0) { src = hi ? wq_i : wq_r; if (hi) sgn = -1.f; }
            else        { src = hi ? wq_r : wq_i; }
            sgn *= kQScaleL2;
        } else {
            stride = 512;
            col = (g >= 4) ? d + 256 : d;
            if ((g & 1) == 0) { src = hi ? wkv_i : wkv_r; if (hi) sgn = -1.f; }
            else              { src = hi ? wkv_r : wkv_i; }
        }
        short4v v;
        #pragma unroll
        for (int j = 0; j < 4; ++j)
            v[j] = (short)bf16b(src[(long)(k2 + j) * stride + col] * sgn);
        *(short4v*)(Wbig + base) = v;
    } else {
        const long o = base - 786432;
        const int c = (int)(o >> 9);
        const int k = (int)(o & 511);
        const bool hi = k >= 256;
        const int k2 = hi ? k - 256 : k;
        const float* src;
        float sgn = 1.f;
        int col;
        if (c < 256) { col = c;       src = hi ? wo_i : wo_r; if (hi) sgn = -1.f; }
        else         { col = c - 256; src = hi ? wo_r : wo_i; }
        short4v v;
        #pragma unroll
        for (int j = 0; j < 4; ++j)
            v[j] = (short)bf16b(src[(long)(k2 + j) * 256 + col] * sgn);
        *(short4v*)(WoT + o) = v;
    }
}

// ---------------------------------------------------------------------------
// QKV projection GEMM. vT stored [bh][32 d][2048 n] with n's bits 2<->3
// SWAPPED inside each 32-key group (PV B-frag permutation pre-applied).
// ---------------------------------------------------------------------------
__global__ __launch_bounds__(256, 2) void gemm_proj(
    const float* __restrict__ xr_g, const float* __restrict__ xi_g,
    const u16* __restrict__ BT,
    u16* __restrict__ qr, u16* __restrict__ qi, u16* __restrict__ kr,
    u16* __restrict__ ki, u16* __restrict__ vrT, u16* __restrict__ viT)
{
    __shared__ __align__(16) u16 sA[128 * 32];
    __shared__ __align__(16) u16 sB[128 * 32];
    const int tid = threadIdx.x;
    const int lane = tid & 63, l31 = lane & 31, lh = lane >> 5;
    const int w = tid >> 6, wrow = w & 1, wcol = w >> 1;
    const int srow = tid >> 2, sseg = tid & 3;
    const int n0 = blockIdx.x * 128, m0 = blockIdx.y * 128;

    floatx16 a00 = {0}, a01 = {0}, a10 = {0}, a11 = {0};

    for (int kt = 0; kt < 512; kt += 32) {
        __syncthreads();
        const float* xbase = (kt < 256) ? xr_g : xi_g;
        const int kc = (kt & 255) + sseg * 8;
        #pragma unroll
        for (int i = 0; i < 2; ++i) {
            const int r = srow + i * 64;
            {
                const float* src = xbase + (long)(m0 + r) * 256 + kc;
                const float4 f0 = *(const float4*)(src);
                const float4 f1 = *(const float4*)(src + 4);
                short8 v;
                v[0] = (short)bf16b(f0.x); v[1] = (short)bf16b(f0.y);
                v[2] = (short)bf16b(f0.z); v[3] = (short)bf16b(f0.w);
                v[4] = (short)bf16b(f1.x); v[5] = (short)bf16b(f1.y);
                v[6] = (short)bf16b(f1.z); v[7] = (short)bf16b(f1.w);
                *(short8*)(sA + r * 32 + sseg * 8) = v;
            }
            *(short8*)(sB + r * 32 + sseg * 8) =
                *(const short8*)(BT + (long)(n0 + r) * 512 + kt + sseg * 8);
        }
        __syncthreads();
        #pragma unroll
        for (int s = 0; s < 2; ++s) {
            const int ko = s * 16 + lh * 8;
            const short8 fa0 = *(const short8*)(sA + (wrow * 64 + l31) * 32 + ko);
            const short8 fa1 = *(const short8*)(sA + (wrow * 64 + 32 + l31) * 32 + ko);
            const short8 fb0 = *(const short8*)(sB + (wcol * 64 + l31) * 32 + ko);
            const short8 fb1 = *(const short8*)(sB + (wcol * 64 + 32 + l31) * 32 + ko);
            a00 = MFMA_BF16(fa0, fb0, a00);
            a01 = MFMA_BF16(fa0, fb1, a01);
            a10 = MFMA_BF16(fa1, fb0, a10);
            a11 = MFMA_BF16(fa1, fb1, a11);
        }
    }

    floatx16 accs[2][2] = {{a00, a01}, {a10, a11}};
    #pragma unroll
    for (int rt = 0; rt < 2; ++rt) {
        #pragma unroll
        for (int ct = 0; ct < 2; ++ct) {
            const int colb = n0 + wcol * 64 + ct * 32;
            const int g = colb >> 8;
            const int h = (colb & 255) >> 5;
            if (g < 4) {
                u16* pl = (g == 0) ? qr : (g == 1) ? qi : (g == 2) ? kr : ki;
                #pragma unroll
                for (int reg = 0; reg < 16; ++reg) {
                    const int row = m0 + wrow * 64 + rt * 32 + (reg & 3) + 8 * (reg >> 2) + 4 * lh;
                    const int b = row >> 11, nn = row & 2047;
                    pl[(((long)(b * 8 + h)) * 2048 + nn) * 32 + l31] = bf16b(accs[rt][ct][reg]);
                }
            } else {
                u16* pl = (g == 4) ? vrT : viT;
                #pragma unroll
                for (int reg = 0; reg < 16; ++reg) {
                    const int row = m0 + wrow * 64 + rt * 32 + (reg & 3) + 8 * (reg >> 2) + 4 * lh;
                    const int b = row >> 11, nn = row & 2047;
                    // pre-apply PV permutation: swap bits 2<->3 of n
                    const int np = (nn & ~12) | ((nn & 4) << 1) | ((nn & 8) >> 1);
                    pl[(((long)(b * 8 + h)) * 32 + l31) * 2048 + np] = bf16b(accs[rt][ct][reg]);
                }
            }
        }
    }
}

// ---------------------------------------------------------------------------
// MFMA flash attention v4 (R5 skeleton + zero-shuffle P-repack).
// S^T = K.Q^T (C-layout: lane = query col, regs = key rows).
// PV B-frags are 4 v_perm packs of the lane's OWN exp regs; the required
// key permutation (bits 2<->3 of n) is pre-applied to V's global layout.
// Double-buffered K/V staging, 1 barrier per 32-key tile, 2 blocks/CU.
// ---------------------------------------------------------------------------
__global__ __launch_bounds__(256, 2) void attn_kernel(
    const u16* __restrict__ qr_g, const u16* __restrict__ qi_g,
    const u16* __restrict__ kr_g, const u16* __restrict__ ki_g,
    const u16* __restrict__ vrT_g, const u16* __restrict__ viT_g,
    u16* __restrict__ xo)
{
    __shared__ __align__(16) u16 smem[2][2][64 * 40];   // [K/V][buf] 20.0 KiB

    const int tid = threadIdx.x;
    const int lane = tid & 63, l31 = lane & 31, lh = lane >> 5;
    const int w = tid >> 6, strip = w & 1, qtype = w >> 1;
    const int bh = blockIdx.x;          // bh-major: per-XCD L2 locality
    const int i0 = blockIdx.y * 64;
    const long base = (long)bh * kN * kDH;

    // Q B-frags (lane = query column l31, k = d)
    const u16* qg = (qtype ? qi_g : qr_g) + base;
    short8 qB0, qB1;
    {
        const u16* qp = qg + (long)(i0 + strip * 32 + l31) * kDH;
        qB0 = *(const short8*)(qp + lh * 8);
        qB1 = *(const short8*)(qp + 16 + lh * 8);
    }

    // staging roles: one b128 per thread for K and V
    const int srow = tid & 63;   // K: bigkey row | V: vcol row
    const int sseg = tid >> 6;   // 8-elem segment
    const u16* kptr = ((srow < 32) ? kr_g : ki_g) + base
                    + (long)(srow & 31) * kDH + sseg * 8;
    const u16* vptr = ((srow < 32) ? vrT_g : viT_g)
                    + ((long)bh * 32 + (srow & 31)) * kN + sseg * 8;

    short8 kreg = *(const short8*)kptr;
    short8 vreg = *(const short8*)vptr;

    floatx16 U0r = {0}, U0i = {0}, U1r = {0}, U1i = {0};
    float La0 = 0.f, La1 = 0.f;

    for (int t = 0; t < 64; ++t) {
        u16* bK = smem[0][t & 1];
        u16* bV = smem[1][t & 1];
        *(short8*)(bK + srow * 40 + sseg * 8) = kreg;
        *(short8*)(bV + srow * 40 + sseg * 8) = vreg;
        __syncthreads();
        if (t < 63) {
            // K layout [bh][n][dh]: one 32-key tile = 1024 elems
            kreg = *(const short8*)(kptr + (long)(t + 1) * 1024);
            // vT layout [d][n]: one 32-key tile = 32 elems along n
            vreg = *(const short8*)(vptr + (t + 1) * 32);
        }

        // S^T: A = K rows (kr: 0..31, ki: 32..63), B = Q
        const short8 ka0 = *(const short8*)(bK + l31 * 40 + lh * 8);
        const short8 ka1 = *(const short8*)(bK + l31 * 40 + 16 + lh * 8);
        const short8 kb0 = *(const short8*)(bK + (32 + l31) * 40 + lh * 8);
        const short8 kb1 = *(const short8*)(bK + (32 + l31) * 40 + 16 + lh * 8);
        floatx16 S0 = {0}, S1 = {0};
        S0 = MFMA_BF16(ka0, qB0, S0);
        S0 = MFMA_BF16(ka1, qB1, S0);
        S1 = MFMA_BF16(kb0, qB0, S1);
        S1 = MFMA_BF16(kb1, qB1, S1);

        float e0[16], e1[16];
        #pragma unroll
        for (int r = 0; r < 16; ++r) {
            e0[r] = __builtin_amdgcn_exp2f(S0[r]);
            La0 += e0[r];
        }
        #pragma unroll
        for (int r = 0; r < 16; ++r) {
            e1[r] = __builtin_amdgcn_exp2f(S1[r]);
            La1 += e1[r];
        }
        // PV B-frags from own regs (permutation pre-applied in V layout)
        const short8 F0a = mk8(&e0[0]);
        const short8 F0b = mk8(&e0[8]);
        const short8 F1a = mk8(&e1[0]);
        const short8 F1b = mk8(&e1[8]);

        // V^T A-frags (vr rows 0..31, vi rows 32..63)
        const short8 va0 = *(const short8*)(bV + l31 * 40 + lh * 8);
        const short8 va1 = *(const short8*)(bV + l31 * 40 + 16 + lh * 8);
        const short8 vb0 = *(const short8*)(bV + (32 + l31) * 40 + lh * 8);
        const short8 vb1 = *(const short8*)(bV + (32 + l31) * 40 + 16 + lh * 8);

        U0r = MFMA_BF16(va0, F0a, U0r);
        U0r = MFMA_BF16(va1, F0b, U0r);
        U0i = MFMA_BF16(vb0, F0a, U0i);
        U0i = MFMA_BF16(vb1, F0b, U0i);
        U1r = MFMA_BF16(va0, F1a, U1r);
        U1r = MFMA_BF16(va1, F1b, U1r);
        U1i = MFMA_BF16(vb0, F1a, U1i);
        U1i = MFMA_BF16(vb1, F1b, U1i);
    }

    La0 += __shfl_xor(La0, 32);
    La1 += __shfl_xor(La1, 32);
    const float iL0 = 1.f / La0, iL1 = 1.f / La1;

    float po_r[16], po_i[16];
    #pragma unroll
    for (int r = 0; r < 16; ++r) {
        if (qtype == 0) {
            po_r[r] =  U0r[r] * iL0 - U1i[r] * iL1;
            po_i[r] =  U0i[r] * iL0 + U1r[r] * iL1;
        } else {
            po_r[r] = -U0i[r] * iL0 - U1r[r] * iL1;
            po_i[r] =  U0r[r] * iL0 - U1i[r] * iL1;
        }
    }

    __syncthreads();   // done with K/V buffers; overlay combine scratch
    float* sC = (float*)smem;   // [strip][2][32 d][33]
    if (qtype == 1) {
        float* dst = sC + strip * (2 * 32 * 33);
        #pragma unroll
        for (int r = 0; r < 16; ++r) {
            const int d = (r & 3) + 8 * (r >> 2) + 4 * lh;
            dst[d * 33 + l31] = po_r[r];
            dst[32 * 33 + d * 33 + l31] = po_i[r];
        }
    }
    __syncthreads();
    if (qtype == 0) {
        const float* src = sC + strip * (2 * 32 * 33);
        const int b = bh >> 3, h = bh & 7;
        u16* xrow = xo + ((long)(b * 2048 + i0 + strip * 32 + l31)) * 512 + h * 32;
        #pragma unroll
        for (int g = 0; g < 4; ++g) {
            const int d0 = 8 * g + 4 * lh;
            union { unsigned u[2]; uint2 v; } pr, pi;
            pr.u[0] = pack2(po_r[4 * g + 0] + src[(d0 + 0) * 33 + l31],
                            po_r[4 * g + 1] + src[(d0 + 1) * 33 + l31]);
            pr.u[1] = pack2(po_r[4 * g + 2] + src[(d0 + 2) * 33 + l31],
                            po_r[4 * g + 3] + src[(d0 + 3) * 33 + l31]);
            pi.u[0] = pack2(po_i[4 * g + 0] + src[32 * 33 + (d0 + 0) * 33 + l31],
                            po_i[4 * g + 1] + src[32 * 33 + (d0 + 1) * 33 + l31]);
            pi.u[1] = pack2(po_i[4 * g + 2] + src[32 * 33 + (d0 + 2) * 33 + l31],
                            po_i[4 * g + 3] + src[32 * 33 + (d0 + 3) * 33 + l31]);
            *(uint2*)(xrow + d0) = pr.v;
            *(uint2*)(xrow + 256 + d0) = pi.v;
        }
    }
}

// ---------------------------------------------------------------------------
// Output projection GEMM (unchanged).
// ---------------------------------------------------------------------------
__global__ __launch_bounds__(256, 2) void gemm_oproj(
    const u16* __restrict__ Xo, const u16* __restrict__ BT, float* __restrict__ out)
{
    __shared__ __align__(16) u16 sA[128 * 32];
    __shared__ __align__(16) u16 sB[128 * 32];
    const int tid = threadIdx.x;
    const int lane = tid & 63, l31 = lane & 31, lh = lane >> 5;
    const int w = tid >> 6, wrow = w & 1, wcol = w >> 1;
    const int srow = tid >> 2, sseg = tid & 3;
    const int n0 = blockIdx.x * 128, m0 = blockIdx.y * 128;

    floatx16 a00 = {0}, a01 = {0}, a10 = {0}, a11 = {0};

    for (int kt = 0; kt < 512; kt += 32) {
        __syncthreads();
        #pragma unroll
        for (int i = 0; i < 2; ++i) {
            const int r = srow + i * 64;
            *(short8*)(sA + r * 32 + sseg * 8) =
                *(const short8*)(Xo + (long)(m0 + r) * 512 + kt + sseg * 8);
            *(short8*)(sB + r * 32 + sseg * 8) =
                *(const short8*)(BT + (long)(n0 + r) * 512 + kt + sseg * 8);
        }
        __syncthreads();
        #pragma unroll
        for (int s = 0; s < 2; ++s) {
            const int ko = s * 16 + lh * 8;
            const short8 fa0 = *(const short8*)(sA + (wrow * 64 + l31) * 32 + ko);
            const short8 fa1 = *(const short8*)(sA + (wrow * 64 + 32 + l31) * 32 + ko);
            const short8 fb0 = *(const short8*)(sB + (wcol * 64 + l31) * 32 + ko);
            const short8 fb1 = *(const short8*)(sB + (wcol * 64 + 32 + l31) * 32 + ko);
            a00 = MFMA_BF16(fa0, fb0, a00);
            a01 = MFMA_BF16(fa0, fb1, a01);
            a10 = MFMA_BF16(fa1, fb0, a10);
            a11 = MFMA_BF16(fa1, fb1, a11);
        }
    }

    floatx16 accs[2][2] = {{a00, a01}, {a10, a11}};
    #pragma unroll
    for (int rt = 0; rt < 2; ++rt) {
        #pragma unroll
        for (int ct = 0; ct < 2; ++ct) {
            const int colb = n0 + wcol * 64 + ct * 32;
            #pragma unroll
            for (int reg = 0; reg < 16; ++reg) {
                const int row = m0 + wrow * 64 + rt * 32 + (reg & 3) + 8 * (reg >> 2) + 4 * lh;
                const int col = colb + l31;
                const float val = accs[rt][ct][reg];
                if (colb < 256) out[(long)row * 512 + col * 2] = val;
                else            out[(long)row * 512 + (col - 256) * 2 + 1] = val;
            }
        }
    }
}

extern "C" void kernel_launch(void* const* d_in, const int* in_sizes, int n_in,
                              void* d_out, int out_size, void* d_ws, size_t ws_size,
                              hipStream_t stream) {
    const float* xr    = (const float*)d_in[0];
    const float* xi    = (const float*)d_in[1];
    const float* wq_r  = (const float*)d_in[2];
    const float* wq_i  = (const float*)d_in[3];
    const float* wkv_r = (const float*)d_in[4];
    const float* wkv_i = (const float*)d_in[5];
    const float* wo_r  = (const float*)d_in[6];
    const float* wo_i  = (const float*)d_in[7];
    float* out = (float*)d_out;

    u16* ws16 = (u16*)d_ws;
    u16* qr   = ws16 + 0 * kPlane;
    u16* qi   = ws16 + 1 * kPlane;
    u16* kr   = ws16 + 2 * kPlane;
    u16* ki   = ws16 + 3 * kPlane;
    u16* vrT  = ws16 + 4 * kPlane;
    u16* viT  = ws16 + 5 * kPlane;
    u16* xo   = ws16 + 6 * kPlane;               // 2,097,152 elems
    u16* Wbig = ws16 + 8 * kPlane;               // 786,432 elems
    u16* WoT  = Wbig + 786432;                   // 262,144 elems

    prep_w<<<1024, 256, 0, stream>>>(wq_r, wq_i, wkv_r, wkv_i, wo_r, wo_i, Wbig, WoT);
    gemm_proj<<<dim3(12, 32), 256, 0, stream>>>(xr, xi, Wbig, qr, qi, kr, ki, vrT, viT);
    attn_kernel<<<dim3(kBH, kN / 64), 256, 0, stream>>>(qr, qi, kr, ki, vrT, viT, xo);
    gemm_oproj<<<dim3(4, 32), 256, 0, stream>>>(xo, WoT, out);
}